// Round 1
// baseline (19.671 us; speedup 1.0000x reference)
//
#include <hip/hip_runtime.h>

// 8-qubit effective state (qubits 8..10 of the reference stay |000>).
// Layout: batch element -> one wave (64 lanes); index i in [0,256):
//   i = lane*4 + j, lane = i[7:2], j = i[1:0]  (i bit b corresponds to
//   qubit q = 7-b of the reference).
// RY(q) pairs amplitudes differing in bit (7-q); CNOT ring q -> (q+1)%8.

#define N_ANGLES 168  // (M+1)*NV = 21*8

__device__ __forceinline__ void ry_layer(int lane, const float* __restrict__ tb,
                                         float& s0, float& s1, float& s2, float& s3) {
    // q = 0..5 : bit = 7-q, lane bit lb = 5-q  -> cross-lane
    #pragma unroll
    for (int q = 0; q < 6; ++q) {
        const float cv = tb[2 * q];
        const float sv = tb[2 * q + 1];
        const int lb = 5 - q;
        const int mask = 1 << lb;
        const float sg = ((lane >> lb) & 1) ? -sv : sv;
        const float p0 = __shfl_xor(s0, mask);
        const float p1 = __shfl_xor(s1, mask);
        const float p2 = __shfl_xor(s2, mask);
        const float p3 = __shfl_xor(s3, mask);
        s0 = cv * s0 + sg * p0;
        s1 = cv * s1 + sg * p1;
        s2 = cv * s2 + sg * p2;
        s3 = cv * s3 + sg * p3;
    }
    // q = 6 : bit 1 (local), pairs (0,2) and (1,3)
    {
        const float cv = tb[12], sv = tb[13];
        const float n0 = cv * s0 + sv * s2;
        const float n2 = cv * s2 - sv * s0;
        const float n1 = cv * s1 + sv * s3;
        const float n3 = cv * s3 - sv * s1;
        s0 = n0; s1 = n1; s2 = n2; s3 = n3;
    }
    // q = 7 : bit 0 (local), pairs (0,1) and (2,3)
    {
        const float cv = tb[14], sv = tb[15];
        const float n0 = cv * s0 + sv * s1;
        const float n1 = cv * s1 - sv * s0;
        const float n2 = cv * s2 + sv * s3;
        const float n3 = cv * s3 - sv * s2;
        s0 = n0; s1 = n1; s2 = n2; s3 = n3;
    }
}

__global__ __launch_bounds__(256) void qae_kernel(const float* __restrict__ x,
                                                  const float* __restrict__ theta,
                                                  float* __restrict__ out) {
    __shared__ float tab[N_ANGLES * 2];  // interleaved (cos, sin) of theta/2
    const int t = threadIdx.x;
    if (t < N_ANGLES) {
        const float a = theta[t] * 0.5f;
        tab[2 * t]     = cosf(a);
        tab[2 * t + 1] = sinf(a);
    }
    __syncthreads();

    const int lane = t & 63;
    const int wave = t >> 6;
    const int b = blockIdx.x * 4 + wave;

    const float4 xv = *reinterpret_cast<const float4*>(x + (size_t)b * 256 + lane * 4);
    float s0 = xv.x, s1 = xv.y, s2 = xv.z, s3 = xv.w;

    #pragma unroll
    for (int m = 0; m < 20; ++m) {
        const float* tb = &tab[m * 16];
        ry_layer(lane, tb, s0, s1, s2, s3);

        // CNOT ring: control qubit q (bit 7-q) -> target qubit (q+1)%8 (bit 6-q / 7)
        // q = 0..4 : control lane bit (5-q), target lane bit (4-q)
        #pragma unroll
        for (int q = 0; q < 5; ++q) {
            const int cb = 5 - q;
            const int tmask = 1 << (4 - q);
            const bool cond = (lane >> cb) & 1;
            const float p0 = __shfl_xor(s0, tmask);
            const float p1 = __shfl_xor(s1, tmask);
            const float p2 = __shfl_xor(s2, tmask);
            const float p3 = __shfl_xor(s3, tmask);
            s0 = cond ? p0 : s0;
            s1 = cond ? p1 : s1;
            s2 = cond ? p2 : s2;
            s3 = cond ? p3 : s3;
        }
        // q = 5 : control lane bit 0 (i bit 2), target i bit 1 (local) -> swap (s0,s2),(s1,s3)
        {
            const bool cond = lane & 1;
            const float t0 = s0, t1 = s1;
            s0 = cond ? s2 : s0;
            s2 = cond ? t0 : s2;
            s1 = cond ? s3 : s1;
            s3 = cond ? t1 : s3;
        }
        // q = 6 : control i bit 1, target i bit 0 -> swap s2<->s3
        {
            const float tt = s2; s2 = s3; s3 = tt;
        }
        // q = 7 : control i bit 0 (local), target i bit 7 (lane bit 5)
        s1 = __shfl_xor(s1, 32);
        s3 = __shfl_xor(s3, 32);
    }

    // final RY layer (angles 160..167)
    ry_layer(lane, &tab[320], s0, s1, s2, s3);

    // probs_B[b][B] = sum_{i % 8 == B} amp^2 ; B = (lane&1)*4 + j
    float p0 = s0 * s0, p1 = s1 * s1, p2 = s2 * s2, p3 = s3 * s3;
    #pragma unroll
    for (int m = 2; m <= 32; m <<= 1) {
        p0 += __shfl_xor(p0, m);
        p1 += __shfl_xor(p1, m);
        p2 += __shfl_xor(p2, m);
        p3 += __shfl_xor(p3, m);
    }
    if (lane < 2) {
        *reinterpret_cast<float4*>(out + (size_t)b * 8 + lane * 4) =
            make_float4(p0, p1, p2, p3);
    }
}

extern "C" void kernel_launch(void* const* d_in, const int* in_sizes, int n_in,
                              void* d_out, int out_size, void* d_ws, size_t ws_size,
                              hipStream_t stream) {
    const float* x = (const float*)d_in[0];      // [1024, 256]
    const float* theta = (const float*)d_in[1];  // [168]
    float* out = (float*)d_out;                  // [1024, 8]

    // 1024 batch elements, 4 per block (one per wave)
    qae_kernel<<<256, 256, 0, stream>>>(x, theta, out);
}